// Round 1
// baseline (103.578 us; speedup 1.0000x reference)
//
#include <hip/hip_runtime.h>
#include <math.h>

#define NN 384
#define TILE 16

// P[i,j] = (adj>0 && i!=j) ? exp(-lam*dist[i,j]) : 0
__global__ void build_p_kernel(const int* __restrict__ adj,
                               const float* __restrict__ dist,
                               const int* __restrict__ lam_ptr,
                               float* __restrict__ P) {
    int idx = blockIdx.x * blockDim.x + threadIdx.x;
    if (idx >= NN * NN) return;
    int i = idx / NN;
    int j = idx - i * NN;
    float lam = (float)(*lam_ptr);
    float p = 0.0f;
    if (adj[idx] > 0 && i != j) p = expf(-lam * dist[idx]);
    P[idx] = p;
}

// V[o,d] = (od>0 && o!=d && denom>0) ? od/(P[o,d] + (P*P)[o,d]) : 0
__global__ void compute_v_kernel(const float* __restrict__ P,
                                 const float* __restrict__ od,
                                 float* __restrict__ V) {
    __shared__ float As[TILE][TILE + 1];
    __shared__ float Bs[TILE][TILE + 1];
    int ty = threadIdx.y, tx = threadIdx.x;
    int row = blockIdx.y * TILE + ty;  // o
    int col = blockIdx.x * TILE + tx;  // d
    float acc = 0.0f;
    for (int k0 = 0; k0 < NN; k0 += TILE) {
        As[ty][tx] = P[row * NN + k0 + tx];         // P[o, k]
        Bs[ty][tx] = P[(k0 + ty) * NN + col];       // P[k, d]
        __syncthreads();
#pragma unroll
        for (int k = 0; k < TILE; ++k) acc += As[ty][k] * Bs[k][tx];
        __syncthreads();
    }
    int idx = row * NN + col;
    float denom = P[idx] + acc;   // s1 + s2 (o==d case handled by gating below)
    float odv = od[idx];
    float v = 0.0f;
    if (row != col && odv > 0.0f && denom > 0.0f) v = odv / denom;
    V[idx] = v;
}

// out[i,j] = P[i,j] * ( V[i,j] + sum_d V[i,d]*P[j,d] + sum_o P[o,i]*V[o,j] )
__global__ void flows_kernel(const float* __restrict__ P,
                             const float* __restrict__ V,
                             float* __restrict__ out) {
    __shared__ float Vr[TILE][TILE + 1];  // V[i0+ty, k0+tx]
    __shared__ float Pr[TILE][TILE + 1];  // P[j0+ty, k0+tx]
    __shared__ float Pc[TILE][TILE + 1];  // P[k0+ty, i0+tx]
    __shared__ float Vc[TILE][TILE + 1];  // V[k0+ty, j0+tx]
    int ty = threadIdx.y, tx = threadIdx.x;
    int i0 = blockIdx.y * TILE, j0 = blockIdx.x * TILE;
    int i = i0 + ty, j = j0 + tx;
    float acc2 = 0.0f, acc3 = 0.0f;
    for (int k0 = 0; k0 < NN; k0 += TILE) {
        Vr[ty][tx] = V[(i0 + ty) * NN + k0 + tx];
        Pr[ty][tx] = P[(j0 + ty) * NN + k0 + tx];
        Pc[ty][tx] = P[(k0 + ty) * NN + i0 + tx];
        Vc[ty][tx] = V[(k0 + ty) * NN + j0 + tx];
        __syncthreads();
#pragma unroll
        for (int k = 0; k < TILE; ++k) {
            acc2 += Vr[ty][k] * Pr[tx][k];  // C2[i,j] += V[i,k]*P[j,k]
            acc3 += Pc[k][ty] * Vc[k][tx];  // C3[i,j] += P[k,i]*V[k,j]
        }
        __syncthreads();
    }
    int idx = i * NN + j;
    out[idx] = P[idx] * (V[idx] + acc2 + acc3);
}

extern "C" void kernel_launch(void* const* d_in, const int* in_sizes, int n_in,
                              void* d_out, int out_size, void* d_ws, size_t ws_size,
                              hipStream_t stream) {
    const float* od   = (const float*)d_in[0];
    const int*   adj  = (const int*)d_in[1];
    const float* dist = (const float*)d_in[2];
    const int*   lam  = (const int*)d_in[3];
    // d_in[4] = capacity (unused: max_iter=1, BPR update is post-output)
    float* out = (float*)d_out;

    float* P = (float*)d_ws;
    float* V = P + NN * NN;

    dim3 blk1(256);
    dim3 grd1((NN * NN + 255) / 256);
    build_p_kernel<<<grd1, blk1, 0, stream>>>(adj, dist, lam, P);

    dim3 blk2(TILE, TILE);
    dim3 grd2(NN / TILE, NN / TILE);
    compute_v_kernel<<<grd2, blk2, 0, stream>>>(P, od, V);
    flows_kernel<<<grd2, blk2, 0, stream>>>(P, V, out);
}

// Round 2
// 75.149 us; speedup vs baseline: 1.3783x; 1.3783x over previous
//
#include <hip/hip_runtime.h>
#include <math.h>

#define NN 384
#define NT 24              // NN/16 tiles per dim
#define NTILES (NT * NT)   // 576

typedef __attribute__((ext_vector_type(8))) short short8;  // 8 bf16 (4 VGPRs)
typedef __attribute__((ext_vector_type(4))) float v4f;     // 4 fp32 acc

__device__ __forceinline__ unsigned short f2bf(float f) {
    union { float f; unsigned u; } v; v.f = f;
    unsigned r = (v.u + 0x7FFFu + ((v.u >> 16) & 1u)) >> 16;
    return (unsigned short)r;
}
__device__ __forceinline__ float bf2f(unsigned short h) {
    union { unsigned u; float f; } v; v.u = ((unsigned)h) << 16;
    return v.f;
}

// K1: P16[i][j] = bf16(exp(-lam*dist) gated), PT16 = transpose. 576 blocks x 256.
__global__ void build_p_kernel(const int* __restrict__ adj,
                               const float* __restrict__ dist,
                               const int* __restrict__ lam_ptr,
                               unsigned short* __restrict__ P16,
                               unsigned short* __restrict__ PT16) {
    int idx = blockIdx.x * 256 + threadIdx.x;   // exactly NN*NN threads
    int i = idx / NN;
    int j = idx - i * NN;
    float lam = (float)(*lam_ptr);
    float p = (adj[idx] > 0 && i != j) ? expf(-lam * dist[idx]) : 0.0f;
    unsigned short h = f2bf(p);
    P16[idx] = h;
    PT16[j * NN + i] = h;
}

// K2: one wave per 16x16 tile of S = P*P (bf16 MFMA, global-direct fragments),
// then V = od/(P + S) gated. Writes V32 (fp32), V16, VT16.
__global__ __launch_bounds__(64) void v_kernel(const unsigned short* __restrict__ P16,
                                               const unsigned short* __restrict__ PT16,
                                               const float* __restrict__ od,
                                               float* __restrict__ V32,
                                               unsigned short* __restrict__ V16,
                                               unsigned short* __restrict__ VT16) {
    int t = blockIdx.x;
    int i0 = (t / NT) * 16, j0 = (t % NT) * 16;
    int lane = threadIdx.x;
    int col = lane & 15, quad = lane >> 4;
    v4f acc = {0.f, 0.f, 0.f, 0.f};
    // A[m=lane&15][k=quad*8+j] from P16 rows; B[k=quad*8+j][n=lane&15] from PT16 rows.
    const short8* arow = (const short8*)(P16 + (i0 + col) * NN + quad * 8);
    const short8* brow = (const short8*)(PT16 + (j0 + col) * NN + quad * 8);
#pragma unroll
    for (int k0 = 0; k0 < NN / 32; ++k0) {
        short8 a = arow[k0 * 4];   // +32 bf16 per step = 4 short8
        short8 b = brow[k0 * 4];
        acc = __builtin_amdgcn_mfma_f32_16x16x32_bf16(a, b, acc, 0, 0, 0);
    }
#pragma unroll
    for (int r = 0; r < 4; ++r) {
        int i = i0 + quad * 4 + r, j = j0 + col;
        int idx = i * NN + j;
        float denom = bf2f(P16[idx]) + acc[r];
        float o = od[idx];
        float v = (i != j && o > 0.0f && denom > 0.0f) ? o / denom : 0.0f;
        V32[idx] = v;
        unsigned short h = f2bf(v);
        V16[idx] = h;
        VT16[j * NN + i] = h;
    }
}

// K3: one wave per 16x16 tile: W = V*P^T (A=V16 rows, Bt=P16 rows),
// U = P^T*V (A=PT16 rows, Bt=VT16 rows); out = p_exact*(V32 + W + U).
__global__ __launch_bounds__(64) void flows_kernel(const unsigned short* __restrict__ P16,
                                                   const unsigned short* __restrict__ PT16,
                                                   const unsigned short* __restrict__ V16,
                                                   const unsigned short* __restrict__ VT16,
                                                   const float* __restrict__ V32,
                                                   const int* __restrict__ adj,
                                                   const float* __restrict__ dist,
                                                   const int* __restrict__ lam_ptr,
                                                   float* __restrict__ out) {
    int t = blockIdx.x;
    int i0 = (t / NT) * 16, j0 = (t % NT) * 16;
    int lane = threadIdx.x;
    int col = lane & 15, quad = lane >> 4;
    v4f accW = {0.f, 0.f, 0.f, 0.f};
    v4f accU = {0.f, 0.f, 0.f, 0.f};
    const short8* aW = (const short8*)(V16 + (i0 + col) * NN + quad * 8);
    const short8* bW = (const short8*)(P16 + (j0 + col) * NN + quad * 8);
    const short8* aU = (const short8*)(PT16 + (i0 + col) * NN + quad * 8);
    const short8* bU = (const short8*)(VT16 + (j0 + col) * NN + quad * 8);
#pragma unroll
    for (int k0 = 0; k0 < NN / 32; ++k0) {
        short8 a0 = aW[k0 * 4];
        short8 b0 = bW[k0 * 4];
        short8 a1 = aU[k0 * 4];
        short8 b1 = bU[k0 * 4];
        accW = __builtin_amdgcn_mfma_f32_16x16x32_bf16(a0, b0, accW, 0, 0, 0);
        accU = __builtin_amdgcn_mfma_f32_16x16x32_bf16(a1, b1, accU, 0, 0, 0);
    }
    float lam = (float)(*lam_ptr);
#pragma unroll
    for (int r = 0; r < 4; ++r) {
        int i = i0 + quad * 4 + r, j = j0 + col;
        int idx = i * NN + j;
        float p = (adj[idx] > 0 && i != j) ? expf(-lam * dist[idx]) : 0.0f;
        out[idx] = p * (V32[idx] + accW[r] + accU[r]);
    }
}

extern "C" void kernel_launch(void* const* d_in, const int* in_sizes, int n_in,
                              void* d_out, int out_size, void* d_ws, size_t ws_size,
                              hipStream_t stream) {
    const float* od   = (const float*)d_in[0];
    const int*   adj  = (const int*)d_in[1];
    const float* dist = (const float*)d_in[2];
    const int*   lam  = (const int*)d_in[3];
    // d_in[4] = capacity (unused: max_iter=1, BPR update happens after output)
    float* out = (float*)d_out;

    // workspace layout (all 16B-aligned: NN*NN*2 = 294912 bytes per bf16 array)
    unsigned short* P16  = (unsigned short*)d_ws;
    unsigned short* PT16 = P16 + NN * NN;
    unsigned short* V16  = PT16 + NN * NN;
    unsigned short* VT16 = V16 + NN * NN;
    float*          V32  = (float*)(VT16 + NN * NN);

    build_p_kernel<<<NTILES, 256, 0, stream>>>(adj, dist, lam, P16, PT16);
    v_kernel<<<NTILES, 64, 0, stream>>>(P16, PT16, od, V32, V16, VT16);
    flows_kernel<<<NTILES, 64, 0, stream>>>(P16, PT16, V16, VT16, V32, adj, dist, lam, out);
}